// Round 18
// baseline (199.843 us; speedup 1.0000x reference)
//
#include <hip/hip_runtime.h>
#include <stdint.h>

typedef __bf16 bf16;
typedef __bf16 bf16x2 __attribute__((ext_vector_type(2)));
typedef __bf16 bf16x4 __attribute__((ext_vector_type(4)));
typedef __bf16 bf16x8 __attribute__((ext_vector_type(8)));
typedef float f32x4 __attribute__((ext_vector_type(4)));
typedef unsigned int u32;
typedef u32 u32x4 __attribute__((ext_vector_type(4)));

#define D_MODEL 1024
#define NHEADS 16
#define HEADDIM 64
#define SEQ 2048
#define NBATCH 2

__device__ __forceinline__ void async_load16(const void* g, void* l) {
  __builtin_amdgcn_global_load_lds(
      (__attribute__((address_space(1))) void*)g,
      (__attribute__((address_space(3))) void*)l, 16, 0, 0);
}

__device__ __forceinline__ float fexp2(float x) {
#if __has_builtin(__builtin_amdgcn_exp2f)
  return __builtin_amdgcn_exp2f(x);
#else
  return exp2f(x);
#endif
}

// x.hi32lanes <-> y.lo32lanes
__device__ __forceinline__ void pswap32(u32& x, u32& y) {
  asm("v_permlane32_swap_b32 %0, %1" : "+v"(x), "+v"(y));
}
// x.odd16groups <-> y.even16groups
__device__ __forceinline__ void pswap16(u32& x, u32& y) {
  asm("v_permlane16_swap_b32 %0, %1" : "+v"(x), "+v"(y));
}

// ------- merged LayerNorm + all-weight transpose (1 launch, 5120 blocks) -------
__global__ __launch_bounds__(256)
void ln_and_transpose(const float* __restrict__ x, const float* __restrict__ lw,
                      const float* __restrict__ lb, bf16* __restrict__ y,
                      const float* __restrict__ wq, const float* __restrict__ wk,
                      const float* __restrict__ wv, const float* __restrict__ wo,
                      bf16* __restrict__ WqkvT, bf16* __restrict__ woT) {
  __shared__ float tile[64][65];
  __shared__ float ps[4], pq[4];
  int t = threadIdx.x;
  if (blockIdx.x < 4096) {
    int row = blockIdx.x;
    const float4 v = ((const float4*)(x + (size_t)row * D_MODEL))[t];
    float s = v.x + v.y + v.z + v.w;
    float sq = v.x * v.x + v.y * v.y + v.z * v.z + v.w * v.w;
#pragma unroll
    for (int d = 1; d < 64; d <<= 1) {
      s += __shfl_xor(s, d);
      sq += __shfl_xor(sq, d);
    }
    if ((t & 63) == 0) { ps[t >> 6] = s; pq[t >> 6] = sq; }
    __syncthreads();
    s = ps[0] + ps[1] + ps[2] + ps[3];
    sq = pq[0] + pq[1] + pq[2] + pq[3];
    float mean = s * (1.0f / D_MODEL);
    float var = sq * (1.0f / D_MODEL) - mean * mean;
    float rstd = rsqrtf(var + 1e-5f);
    float4 wv4 = ((const float4*)lw)[t];
    float4 bv = ((const float4*)lb)[t];
    bf16x4 o;
    o[0] = (bf16)((v.x - mean) * rstd * wv4.x + bv.x);
    o[1] = (bf16)((v.y - mean) * rstd * wv4.y + bv.y);
    o[2] = (bf16)((v.z - mean) * rstd * wv4.z + bv.z);
    o[3] = (bf16)((v.w - mean) * rstd * wv4.w + bv.w);
    ((bf16x4*)(y + (size_t)row * D_MODEL))[t] = o;
    return;
  }
  int blk = blockIdx.x - 4096;
  const float* s;
  bf16* d;
  int src_ld, dst_ld;
  if (blk < 768) {
    int wsel = blk >> 8;
    int rem = blk & 255;
    int h = rem >> 4, tr = rem & 15;
    const float* w3 = (wsel == 0) ? wq : (wsel == 1) ? wk : wv;
    s = w3 + (size_t)h * 65536 + (size_t)tr * 64 * 64;
    d = WqkvT + ((size_t)wsel << 20) + (size_t)h * 65536 + (size_t)tr * 64;
    src_ld = 64; dst_ld = 1024;
  } else {
    int r = blk - 768;
    int tr = r >> 4, tc = r & 15;
    s = wo + (size_t)(tr * 64) * 1024 + tc * 64;
    d = woT + (size_t)(tc * 64) * 1024 + tr * 64;
    src_ld = 1024; dst_ld = 1024;
  }
  int rr = t >> 4;
  int cc = (t & 15) << 2;
#pragma unroll
  for (int i = 0; i < 4; ++i) {
    float4 v = *(const float4*)&s[(size_t)(rr + i * 16) * src_ld + cc];
    tile[rr + i * 16][cc + 0] = v.x;
    tile[rr + i * 16][cc + 1] = v.y;
    tile[rr + i * 16][cc + 2] = v.z;
    tile[rr + i * 16][cc + 3] = v.w;
  }
  __syncthreads();
#pragma unroll
  for (int i = 0; i < 4; ++i) {
    int drow = rr + i * 16;
    bf16x4 o;
    o[0] = (bf16)tile[cc + 0][drow];
    o[1] = (bf16)tile[cc + 1][drow];
    o[2] = (bf16)tile[cc + 2][drow];
    o[3] = (bf16)tile[cc + 3][drow];
    *(bf16x4*)&d[(size_t)drow * dst_ld + cc] = o;
  }
}

// ------------- GEMM: C[M][N] = A[M][K=1024] * Bt[N][K=1024]^T -------------
template <int MODE, int BM, int BN>
__global__ __launch_bounds__(256)
void gemm_bt(const bf16* __restrict__ A, const bf16* __restrict__ Bt,
             int ntn, void* __restrict__ p0, void* __restrict__ p1,
             void* __restrict__ p2) {
  constexpr int NWR = BM / 64;
  constexpr int NWC = 4 / NWR;
  constexpr int NJ = BN / (16 * NWC);
  __shared__ __align__(16) bf16 As[2][BM * 64];
  __shared__ __align__(16) bf16 Bs[2][BN * 64];
  int cpx = gridDim.x >> 3;
  int wg = (blockIdx.x & 7) * cpx + (blockIdx.x >> 3);
  int bm = wg / ntn;
  int bn = wg % ntn;
  int t = threadIdx.x;
  int w = t >> 6, l = t & 63;
  int lg = l >> 4, lo = l & 15;
  int wr = w / NWC, wc = w % NWC;
  const bf16* Ab = A + (size_t)bm * BM * 1024;
  const bf16* Bb = Bt + (size_t)bn * BN * 1024;
  f32x4 acc[4][NJ];
#pragma unroll
  for (int i = 0; i < 4; ++i)
#pragma unroll
    for (int j = 0; j < NJ; ++j) acc[i][j] = (f32x4){0.f, 0.f, 0.f, 0.f};

  auto stage = [&](int bufi, int k0) {
#pragma unroll
    for (int it = 0; it < BM / 32; ++it) {
      int flat = it * 2048 + t * 8;
      int row = flat >> 6, sc = ((flat & 63) >> 3) ^ (row & 7);
      async_load16(Ab + (size_t)row * 1024 + k0 + sc * 8, &As[bufi][it * 2048 + w * 512]);
    }
#pragma unroll
    for (int it = 0; it < BN / 32; ++it) {
      int flat = it * 2048 + t * 8;
      int row = flat >> 6, sc = ((flat & 63) >> 3) ^ (row & 7);
      async_load16(Bb + (size_t)row * 1024 + k0 + sc * 8, &Bs[bufi][it * 2048 + w * 512]);
    }
  };

  stage(0, 0);
  __syncthreads();
  int buf = 0;
  for (int k0 = 0; k0 < 1024; k0 += 64) {
    if (k0 + 64 < 1024) stage(buf ^ 1, k0 + 64);  // async prefetch over compute
#pragma unroll
    for (int kk = 0; kk < 2; ++kk) {
      bf16x8 af[4], bfr[NJ];
#pragma unroll
      for (int i = 0; i < 4; ++i) {
        int row = wr * 64 + i * 16 + lo;
        af[i] = *(const bf16x8*)&As[buf][row * 64 + (((4 * kk + lg) ^ (lo & 7)) * 8)];
      }
#pragma unroll
      for (int j = 0; j < NJ; ++j) {
        int row = wc * (NJ * 16) + j * 16 + lo;
        bfr[j] = *(const bf16x8*)&Bs[buf][row * 64 + (((4 * kk + lg) ^ (lo & 7)) * 8)];
      }
#pragma unroll
      for (int i = 0; i < 4; ++i)
#pragma unroll
        for (int j = 0; j < NJ; ++j)
          acc[i][j] = __builtin_amdgcn_mfma_f32_16x16x32_bf16(af[i], bfr[j], acc[i][j], 0, 0, 0);
    }
    __syncthreads();
    buf ^= 1;
  }

  int mbase = bm * BM + wr * 64;
  int nbase = bn * BN + wc * (NJ * 16);
#pragma unroll
  for (int i = 0; i < 4; ++i) {
#pragma unroll
    for (int j = 0; j < NJ; ++j) {
      int row0 = mbase + i * 16 + lg * 4;
      int col = nbase + j * 16 + lo;
      if (MODE == 0) {
        if (col < 2048) {  // q or k, [b][h][s][e]
          bf16* dst = (bf16*)(col < 1024 ? p0 : p1);
          int c = col & 1023;
          int h = c >> 6, e = c & 63;
#pragma unroll
          for (int r = 0; r < 4; ++r) {
            int row = row0 + r;
            dst[((((size_t)(row >> 11) * NHEADS + h) * SEQ) + (row & 2047)) * HEADDIM + e] =
                (bf16)acc[i][j][r];
          }
        } else {  // v^T [b][h][e][s], packed 4 consecutive s
          int c = col - 2048;
          int h = c >> 6, e = c & 63;
          int b_ = row0 >> 11, s_ = row0 & 2047;
          bf16x4 pk;
          pk[0] = (bf16)acc[i][j][0]; pk[1] = (bf16)acc[i][j][1];
          pk[2] = (bf16)acc[i][j][2]; pk[3] = (bf16)acc[i][j][3];
          *(bf16x4*)&((bf16*)p2)[(((size_t)b_ * NHEADS + h) * HEADDIM + e) * SEQ + s_] = pk;
        }
      } else {
#pragma unroll
        for (int r = 0; r < 4; ++r) {
          int row = row0 + r;
          float xr = ((const float*)p1)[(size_t)row * 1024 + col];
          ((float*)p0)[(size_t)row * 1024 + col] = acc[i][j][r] + xr;
        }
      }
    }
  }
}

// --- causal flash attention (R15 per-wave code + 3-way split-KV, 4 blocks/CU) ---
// 8 waves x 16 q-rows, 512 thr, grid 1024. Per bh: 32 jobs; quad e (one CU) =
// {unsplit tb=7-e} + {3 thirds of tb=8+e}: work (16-2e)+(18+2e) = 34 for all e
// -> exact per-CU balance with 4 concurrent blocks. Fixed-M softmax makes KV
// partials additive. bh pinned to XCD (i&7); slots {c,c+32,c+64,c+96} of a CU
// share bh. In-register P via permlane swaps; K/V LDS-staged (32 KB, dbuf).
__global__ __launch_bounds__(512, 8)
void attn_kernel(const bf16* __restrict__ q, const bf16* __restrict__ k,
                 const bf16* __restrict__ vt, bf16* __restrict__ attn,
                 bf16* __restrict__ pO, float* __restrict__ plsum) {
  __shared__ __align__(16) bf16 Ks[2][64 * 64];
  __shared__ __align__(16) bf16 Vs[2][64 * 64];
  const float C2 = 0.125f * 1.44269504f;
  const float MC = 128.0f * C2;  // fixed softmax shift
  int i = blockIdx.x;            // 0..1023
  int slot = i >> 3;             // 0..127
  int bh = (i & 7) + 8 * (slot & 3);  // 0..31; i&7 == bh&7 -> one XCD per bh
  int ji = slot >> 2;            // 0..31 job index
  int tb, c0, c1, part;
  bool issplit = (ji >= 8);
  if (!issplit) {
    tb = 7 - ji; part = 0;
    c0 = 0; c1 = 2 * tb + 2;
  } else {
    int e = (ji - 8) & 7;
    part = (ji - 8) >> 3;        // 0,1,2
    tb = 8 + e;
    int n = 2 * tb + 2;
    int s0 = (n + 2) / 3, s1 = (n + 1) / 3;
    c0 = (part == 0) ? 0 : ((part == 1) ? s0 : s0 + s1);
    c1 = (part == 0) ? s0 : ((part == 1) ? s0 + s1 : n);
  }
  int b = bh >> 4, h = bh & 15;
  int t = threadIdx.x, w = t >> 6, l = t & 63;
  int lg = l >> 4, lo = l & 15;
  const bf16* qp = q + (size_t)bh * SEQ * HEADDIM;
  const bf16* kp = k + (size_t)bh * SEQ * HEADDIM;
  const bf16* vp = vt + (size_t)bh * HEADDIM * SEQ;
  int q0 = tb * 128 + w * 16;
  int cd = q0 >> 6;        // this wave's diagonal chunk
  int diag_rhs = (w & 3) * 16 + lo;

  bf16x8 qf0 = *(const bf16x8*)&qp[(size_t)(q0 + lo) * HEADDIM + 8 * lg];
  bf16x8 qf1 = *(const bf16x8*)&qp[(size_t)(q0 + lo) * HEADDIM + 32 + 8 * lg];

  auto stage = [&](int bufi, int kv0) {
    int row = t >> 3, c16 = t & 7;
    int sc = c16 ^ (row & 7);
    async_load16(kp + (size_t)(kv0 + row) * HEADDIM + sc * 8, &Ks[bufi][t * 8]);
    async_load16(vp + (size_t)row * SEQ + kv0 + sc * 8, &Vs[bufi][t * 8]);
  };

  f32x4 o[4];
#pragma unroll
  for (int nt = 0; nt < 4; ++nt) o[nt] = (f32x4){0.f, 0.f, 0.f, 0.f};
  float lsum = 0.f;

  int buf = 0;
  stage(0, c0 * 64);
  __syncthreads();

  for (int c = c0; c < c1; ++c) {
    if (c + 1 < c1) stage(buf ^ 1, (c + 1) * 64);  // async prefetch

    if (c <= cd) {  // uniform per-wave: skip fully-masked chunks
      f32x4 s[4];
      __builtin_amdgcn_s_setprio(1);
#pragma unroll
      for (int nt = 0; nt < 4; ++nt) {
        s[nt] = (f32x4){0.f, 0.f, 0.f, 0.f};
        int krow = nt * 16 + lo;
        bf16x8 kf0 = *(const bf16x8*)&Ks[buf][krow * 64 + ((lg ^ (lo & 7)) * 8)];
        bf16x8 kf1 = *(const bf16x8*)&Ks[buf][krow * 64 + (((4 + lg) ^ (lo & 7)) * 8)];
        s[nt] = __builtin_amdgcn_mfma_f32_16x16x32_bf16(kf0, qf0, s[nt], 0, 0, 0);
        s[nt] = __builtin_amdgcn_mfma_f32_16x16x32_bf16(kf1, qf1, s[nt], 0, 0, 0);
      }
      __builtin_amdgcn_s_setprio(0);

      // hoist V fragment reads (LDS): latency hides under exp/pack below
      bf16x8 vf0[4], vf1[4];
#pragma unroll
      for (int nt = 0; nt < 4; ++nt) {
        int vrow = nt * 16 + lo;
        vf0[nt] = *(const bf16x8*)&Vs[buf][vrow * 64 + ((lg ^ (lo & 7)) * 8)];
        vf1[nt] = *(const bf16x8*)&Vs[buf][vrow * 64 + (((4 + lg) ^ (lo & 7)) * 8)];
      }

      if (c == cd) {  // causal mask, diagonal chunk only
#pragma unroll
        for (int nt = 0; nt < 4; ++nt)
#pragma unroll
          for (int r = 0; r < 4; ++r)
            s[nt][r] = (16 * nt + 4 * lg + r <= diag_rhs) ? s[nt][r] : -1e30f;
      }

      // fixed-M softmax + pack to bf16-pair words
      u32 W[4][2];
      float psum = 0.f;
#pragma unroll
      for (int nt = 0; nt < 4; ++nt) {
        float e0 = fexp2(fmaf(s[nt][0], C2, -MC));
        float e1 = fexp2(fmaf(s[nt][1], C2, -MC));
        float e2 = fexp2(fmaf(s[nt][2], C2, -MC));
        float e3 = fexp2(fmaf(s[nt][3], C2, -MC));
        psum += (e0 + e1) + (e2 + e3);
        bf16x2 w0, w1;
        w0[0] = (bf16)e0; w0[1] = (bf16)e1;
        w1[0] = (bf16)e2; w1[1] = (bf16)e3;
        W[nt][0] = __builtin_bit_cast(u32, w0);
        W[nt][1] = __builtin_bit_cast(u32, w1);
      }
      psum += __shfl_xor(psum, 16);
      psum += __shfl_xor(psum, 32);
      lsum += psum;

      // in-register P re-layout: C-frag -> A-frag via 2 swaps per word pair
      u32 t0 = W[0][0], t2 = W[1][0];
      pswap32(t0, t2); pswap16(t0, t2);
      u32 t1 = W[0][1], t3 = W[1][1];
      pswap32(t1, t3); pswap16(t1, t3);
      u32 u0 = W[2][0], u2 = W[3][0];
      pswap32(u0, u2); pswap16(u0, u2);
      u32 u1 = W[2][1], u3 = W[3][1];
      pswap32(u1, u3); pswap16(u1, u3);
      u32x4 pw0 = {t0, t1, t2, t3};
      u32x4 pw1 = {u0, u1, u2, u3};
      bf16x8 pf0 = __builtin_bit_cast(bf16x8, pw0);
      bf16x8 pf1 = __builtin_bit_cast(bf16x8, pw1);

      __builtin_amdgcn_s_setprio(1);
#pragma unroll
      for (int nt = 0; nt < 4; ++nt) {
        o[nt] = __builtin_amdgcn_mfma_f32_16x16x32_bf16(pf0, vf0[nt], o[nt], 0, 0, 0);
        o[nt] = __builtin_amdgcn_mfma_f32_16x16x32_bf16(pf1, vf1[nt], o[nt], 0, 0, 0);
      }
      __builtin_amdgcn_s_setprio(0);
    }

    __syncthreads();  // drains prefetch + all waves done with buf
    buf ^= 1;
  }

  if (!issplit) {
#pragma unroll
    for (int r = 0; r < 4; ++r) {
      float ls = __shfl(lsum, (l & 48) | (4 * lg + r));
      float inv = 1.0f / ls;
      int qrow = q0 + 4 * lg + r;
#pragma unroll
      for (int nt = 0; nt < 4; ++nt)
        attn[((size_t)b * SEQ + qrow) * D_MODEL + h * HEADDIM + nt * 16 + lo] =
            (bf16)(o[nt][r] * inv);
    }
  } else {  // write bf16 partial O + f32 partial lsum (part 0..2)
#pragma unroll
    for (int r = 0; r < 4; ++r) {
      float ls = __shfl(lsum, (l & 48) | (4 * lg + r));
      int prow = q0 - 1024 + 4 * lg + r;  // tb >= 8 -> q0 >= 1024
      if (lo == 0) plsum[(part << 15) + (bh << 10) + prow] = ls;
      size_t base = (((size_t)part * 32 + bh) * 1024 + prow) * 64;
#pragma unroll
      for (int nt = 0; nt < 4; ++nt)
        pO[base + nt * 16 + lo] = (bf16)o[nt][r];
    }
  }
}

// ------------- merge 3-way split-KV partials: rows s in [1024,2048) -------------
__global__ __launch_bounds__(256)
void merge_kernel(const bf16* __restrict__ pO, const float* __restrict__ plsum,
                  bf16* __restrict__ attn) {
  int tid = blockIdx.x * 256 + threadIdx.x;   // 262144 octets
  int bh = tid >> 13;
  int rem = tid & 8191;
  int srow = rem >> 3, q8 = rem & 7;
  int b = bh >> 4, h = bh & 15;
  int lidx = (bh << 10) + srow;
  float lsum = plsum[lidx] + plsum[(1 << 15) + lidx] + plsum[(2 << 15) + lidx];
  float inv = 1.0f / lsum;
  const size_t PSTRIDE = (size_t)32 * 1024 * 64;
  size_t base = (((size_t)bh) * 1024 + srow) * 64 + q8 * 8;
  bf16x8 a0 = *(const bf16x8*)&pO[base];
  bf16x8 a1 = *(const bf16x8*)&pO[PSTRIDE + base];
  bf16x8 a2 = *(const bf16x8*)&pO[2 * PSTRIDE + base];
  bf16x8 o;
#pragma unroll
  for (int e = 0; e < 8; ++e)
    o[e] = (bf16)((((float)a0[e] + (float)a1[e]) + (float)a2[e]) * inv);
  *(bf16x8*)&attn[((size_t)b * SEQ + 1024 + srow) * D_MODEL + h * HEADDIM + q8 * 8] = o;
}

extern "C" void kernel_launch(void* const* d_in, const int* in_sizes, int n_in,
                              void* d_out, int out_size, void* d_ws, size_t ws_size,
                              hipStream_t stream) {
  const float* x = (const float*)d_in[0];
  const float* ln_w = (const float*)d_in[1];
  const float* ln_b = (const float*)d_in[2];
  const float* wq = (const float*)d_in[3];
  const float* wk = (const float*)d_in[4];
  const float* wv = (const float*)d_in[5];
  const float* wo = (const float*)d_in[6];
  float* out = (float*)d_out;
  char* ws = (char*)d_ws;

  bf16* y     = (bf16*)(ws);                     // 8 MB (dead after QKV GEMM)
  bf16* WqkvT = (bf16*)(ws + (8u << 20));        // 6 MB (dead after QKV GEMM)
  bf16* woT   = (bf16*)(ws + (14u << 20));       // 2 MB (live until out-proj)
  bf16* qb    = (bf16*)(ws + (16u << 20));       // 8 MB  [b][h][s][e]
  bf16* kb    = (bf16*)(ws + (24u << 20));       // 8 MB  [b][h][s][e]
  bf16* vtb   = (bf16*)(ws + (32u << 20));       // 8 MB  [b][h][e][s]
  bf16* attnb = (bf16*)(ws + (40u << 20));       // 8 MB  [b*s][h*e]
  // 3-way split-KV scratch aliases y+WqkvT (dead before attn launches):
  bf16*  pO    = (bf16*)(ws);                    // 12 MB [3][32][1024][64] bf16
  float* plsum = (float*)(ws + (12u << 20));     // 384 KB [3][32][1024] f32

  // LayerNorm + all weight transposes, one launch
  ln_and_transpose<<<5120, 256, 0, stream>>>(x, ln_w, ln_b, y, wq, wk, wv, wo,
                                             WqkvT, woT);

  // fused QKV projection: [4096,1024] x [3072,1024]^T, 128x192 tiles (512 = 2/CU)
  gemm_bt<0, 128, 192><<<512, 256, 0, stream>>>(y, WqkvT, 16, qb, kb, vtb);

  // causal flash attention: 1024 blocks x 512 thr (4/CU), 3-way split-KV
  attn_kernel<<<dim3(1024), 512, 0, stream>>>(qb, kb, vtb, attnb, pO, plsum);

  // merge 3-way partials for rows s in [1024, 2048)
  merge_kernel<<<1024, 256, 0, stream>>>(pO, plsum, attnb);

  // output projection + residual: [4096,1024] x [1024,1024]^T + x, 64x128 tiles
  gemm_bt<2, 64, 128><<<512, 256, 0, stream>>>(attnb, woT, 8, out, (void*)x, nullptr);
}

// Round 19
// 101.523 us; speedup vs baseline: 1.9684x; 1.9684x over previous
//
#include <hip/hip_runtime.h>
#include <stdint.h>

typedef __bf16 bf16;
typedef __bf16 bf16x2 __attribute__((ext_vector_type(2)));
typedef __bf16 bf16x4 __attribute__((ext_vector_type(4)));
typedef __bf16 bf16x8 __attribute__((ext_vector_type(8)));
typedef float f32x4 __attribute__((ext_vector_type(4)));
typedef unsigned int u32;
typedef u32 u32x4 __attribute__((ext_vector_type(4)));

#define D_MODEL 1024
#define NHEADS 16
#define HEADDIM 64
#define SEQ 2048
#define NBATCH 2

__device__ __forceinline__ void async_load16(const void* g, void* l) {
  __builtin_amdgcn_global_load_lds(
      (__attribute__((address_space(1))) void*)g,
      (__attribute__((address_space(3))) void*)l, 16, 0, 0);
}

__device__ __forceinline__ float fexp2(float x) {
#if __has_builtin(__builtin_amdgcn_exp2f)
  return __builtin_amdgcn_exp2f(x);
#else
  return exp2f(x);
#endif
}

// x.hi32lanes <-> y.lo32lanes
__device__ __forceinline__ void pswap32(u32& x, u32& y) {
  asm("v_permlane32_swap_b32 %0, %1" : "+v"(x), "+v"(y));
}
// x.odd16groups <-> y.even16groups
__device__ __forceinline__ void pswap16(u32& x, u32& y) {
  asm("v_permlane16_swap_b32 %0, %1" : "+v"(x), "+v"(y));
}

// ------- merged LayerNorm + all-weight transpose (1 launch, 5120 blocks) -------
__global__ __launch_bounds__(256)
void ln_and_transpose(const float* __restrict__ x, const float* __restrict__ lw,
                      const float* __restrict__ lb, bf16* __restrict__ y,
                      const float* __restrict__ wq, const float* __restrict__ wk,
                      const float* __restrict__ wv, const float* __restrict__ wo,
                      bf16* __restrict__ WqkvT, bf16* __restrict__ woT) {
  __shared__ float tile[64][65];
  __shared__ float ps[4], pq[4];
  int t = threadIdx.x;
  if (blockIdx.x < 4096) {
    int row = blockIdx.x;
    const float4 v = ((const float4*)(x + (size_t)row * D_MODEL))[t];
    float s = v.x + v.y + v.z + v.w;
    float sq = v.x * v.x + v.y * v.y + v.z * v.z + v.w * v.w;
#pragma unroll
    for (int d = 1; d < 64; d <<= 1) {
      s += __shfl_xor(s, d);
      sq += __shfl_xor(sq, d);
    }
    if ((t & 63) == 0) { ps[t >> 6] = s; pq[t >> 6] = sq; }
    __syncthreads();
    s = ps[0] + ps[1] + ps[2] + ps[3];
    sq = pq[0] + pq[1] + pq[2] + pq[3];
    float mean = s * (1.0f / D_MODEL);
    float var = sq * (1.0f / D_MODEL) - mean * mean;
    float rstd = rsqrtf(var + 1e-5f);
    float4 wv4 = ((const float4*)lw)[t];
    float4 bv = ((const float4*)lb)[t];
    bf16x4 o;
    o[0] = (bf16)((v.x - mean) * rstd * wv4.x + bv.x);
    o[1] = (bf16)((v.y - mean) * rstd * wv4.y + bv.y);
    o[2] = (bf16)((v.z - mean) * rstd * wv4.z + bv.z);
    o[3] = (bf16)((v.w - mean) * rstd * wv4.w + bv.w);
    ((bf16x4*)(y + (size_t)row * D_MODEL))[t] = o;
    return;
  }
  int blk = blockIdx.x - 4096;
  const float* s;
  bf16* d;
  int src_ld, dst_ld;
  if (blk < 768) {
    int wsel = blk >> 8;
    int rem = blk & 255;
    int h = rem >> 4, tr = rem & 15;
    const float* w3 = (wsel == 0) ? wq : (wsel == 1) ? wk : wv;
    s = w3 + (size_t)h * 65536 + (size_t)tr * 64 * 64;
    d = WqkvT + ((size_t)wsel << 20) + (size_t)h * 65536 + (size_t)tr * 64;
    src_ld = 64; dst_ld = 1024;
  } else {
    int r = blk - 768;
    int tr = r >> 4, tc = r & 15;
    s = wo + (size_t)(tr * 64) * 1024 + tc * 64;
    d = woT + (size_t)(tc * 64) * 1024 + tr * 64;
    src_ld = 1024; dst_ld = 1024;
  }
  int rr = t >> 4;
  int cc = (t & 15) << 2;
#pragma unroll
  for (int i = 0; i < 4; ++i) {
    float4 v = *(const float4*)&s[(size_t)(rr + i * 16) * src_ld + cc];
    tile[rr + i * 16][cc + 0] = v.x;
    tile[rr + i * 16][cc + 1] = v.y;
    tile[rr + i * 16][cc + 2] = v.z;
    tile[rr + i * 16][cc + 3] = v.w;
  }
  __syncthreads();
#pragma unroll
  for (int i = 0; i < 4; ++i) {
    int drow = rr + i * 16;
    bf16x4 o;
    o[0] = (bf16)tile[cc + 0][drow];
    o[1] = (bf16)tile[cc + 1][drow];
    o[2] = (bf16)tile[cc + 2][drow];
    o[3] = (bf16)tile[cc + 3][drow];
    *(bf16x4*)&d[(size_t)drow * dst_ld + cc] = o;
  }
}

// ------------- GEMM: C[M][N] = A[M][K=1024] * Bt[N][K=1024]^T -------------
template <int MODE, int BM, int BN>
__global__ __launch_bounds__(256)
void gemm_bt(const bf16* __restrict__ A, const bf16* __restrict__ Bt,
             int ntn, void* __restrict__ p0, void* __restrict__ p1,
             void* __restrict__ p2) {
  constexpr int NWR = BM / 64;
  constexpr int NWC = 4 / NWR;
  constexpr int NJ = BN / (16 * NWC);
  __shared__ __align__(16) bf16 As[2][BM * 64];
  __shared__ __align__(16) bf16 Bs[2][BN * 64];
  int cpx = gridDim.x >> 3;
  int wg = (blockIdx.x & 7) * cpx + (blockIdx.x >> 3);
  int bm = wg / ntn;
  int bn = wg % ntn;
  int t = threadIdx.x;
  int w = t >> 6, l = t & 63;
  int lg = l >> 4, lo = l & 15;
  int wr = w / NWC, wc = w % NWC;
  const bf16* Ab = A + (size_t)bm * BM * 1024;
  const bf16* Bb = Bt + (size_t)bn * BN * 1024;
  f32x4 acc[4][NJ];
#pragma unroll
  for (int i = 0; i < 4; ++i)
#pragma unroll
    for (int j = 0; j < NJ; ++j) acc[i][j] = (f32x4){0.f, 0.f, 0.f, 0.f};

  auto stage = [&](int bufi, int k0) {
#pragma unroll
    for (int it = 0; it < BM / 32; ++it) {
      int flat = it * 2048 + t * 8;
      int row = flat >> 6, sc = ((flat & 63) >> 3) ^ (row & 7);
      async_load16(Ab + (size_t)row * 1024 + k0 + sc * 8, &As[bufi][it * 2048 + w * 512]);
    }
#pragma unroll
    for (int it = 0; it < BN / 32; ++it) {
      int flat = it * 2048 + t * 8;
      int row = flat >> 6, sc = ((flat & 63) >> 3) ^ (row & 7);
      async_load16(Bb + (size_t)row * 1024 + k0 + sc * 8, &Bs[bufi][it * 2048 + w * 512]);
    }
  };

  stage(0, 0);
  __syncthreads();
  int buf = 0;
  for (int k0 = 0; k0 < 1024; k0 += 64) {
    if (k0 + 64 < 1024) stage(buf ^ 1, k0 + 64);  // async prefetch over compute
#pragma unroll
    for (int kk = 0; kk < 2; ++kk) {
      bf16x8 af[4], bfr[NJ];
#pragma unroll
      for (int i = 0; i < 4; ++i) {
        int row = wr * 64 + i * 16 + lo;
        af[i] = *(const bf16x8*)&As[buf][row * 64 + (((4 * kk + lg) ^ (lo & 7)) * 8)];
      }
#pragma unroll
      for (int j = 0; j < NJ; ++j) {
        int row = wc * (NJ * 16) + j * 16 + lo;
        bfr[j] = *(const bf16x8*)&Bs[buf][row * 64 + (((4 * kk + lg) ^ (lo & 7)) * 8)];
      }
#pragma unroll
      for (int i = 0; i < 4; ++i)
#pragma unroll
        for (int j = 0; j < NJ; ++j)
          acc[i][j] = __builtin_amdgcn_mfma_f32_16x16x32_bf16(af[i], bfr[j], acc[i][j], 0, 0, 0);
    }
    __syncthreads();
    buf ^= 1;
  }

  int mbase = bm * BM + wr * 64;
  int nbase = bn * BN + wc * (NJ * 16);
#pragma unroll
  for (int i = 0; i < 4; ++i) {
#pragma unroll
    for (int j = 0; j < NJ; ++j) {
      int row0 = mbase + i * 16 + lg * 4;
      int col = nbase + j * 16 + lo;
      if (MODE == 0) {
        if (col < 2048) {  // q or k, [b][h][s][e]
          bf16* dst = (bf16*)(col < 1024 ? p0 : p1);
          int c = col & 1023;
          int h = c >> 6, e = c & 63;
#pragma unroll
          for (int r = 0; r < 4; ++r) {
            int row = row0 + r;
            dst[((((size_t)(row >> 11) * NHEADS + h) * SEQ) + (row & 2047)) * HEADDIM + e] =
                (bf16)acc[i][j][r];
          }
        } else {  // v^T [b][h][e][s], packed 4 consecutive s
          int c = col - 2048;
          int h = c >> 6, e = c & 63;
          int b_ = row0 >> 11, s_ = row0 & 2047;
          bf16x4 pk;
          pk[0] = (bf16)acc[i][j][0]; pk[1] = (bf16)acc[i][j][1];
          pk[2] = (bf16)acc[i][j][2]; pk[3] = (bf16)acc[i][j][3];
          *(bf16x4*)&((bf16*)p2)[(((size_t)b_ * NHEADS + h) * HEADDIM + e) * SEQ + s_] = pk;
        }
      } else {
#pragma unroll
        for (int r = 0; r < 4; ++r) {
          int row = row0 + r;
          float xr = ((const float*)p1)[(size_t)row * 1024 + col];
          ((float*)p0)[(size_t)row * 1024 + col] = acc[i][j][r] + xr;
        }
      }
    }
  }
}

// --- causal flash attention (R15 per-wave code + 3-way split-KV, 4 blocks/CU) ---
// 8 waves x 16 q-rows, 512 thr, grid 1024. Per bh: 32 jobs; quad e (one CU) =
// {unsplit tb=7-e} + {3 thirds of tb=8+e}: work (16-2e)+(18+2e) = 34 for all e
// -> exact per-CU balance with 4 concurrent blocks. Fixed-M softmax makes KV
// partials additive. bh pinned to XCD (i&7). NO min-waves launch_bounds arg:
// R18's (512,8) forced VGPR to 32 and spilled everything (250 MB scratch
// fetch). At the natural 56 VGPR, 4 blocks/CU (8 waves/SIMD, 448 VGPR) and
// 128 KB LDS fit anyway.
__global__ __launch_bounds__(512)
void attn_kernel(const bf16* __restrict__ q, const bf16* __restrict__ k,
                 const bf16* __restrict__ vt, bf16* __restrict__ attn,
                 bf16* __restrict__ pO, float* __restrict__ plsum) {
  __shared__ __align__(16) bf16 Ks[2][64 * 64];
  __shared__ __align__(16) bf16 Vs[2][64 * 64];
  const float C2 = 0.125f * 1.44269504f;
  const float MC = 128.0f * C2;  // fixed softmax shift
  int i = blockIdx.x;            // 0..1023
  int slot = i >> 3;             // 0..127
  int bh = (i & 7) + 8 * (slot & 3);  // 0..31; i&7 == bh&7 -> one XCD per bh
  int ji = slot >> 2;            // 0..31 job index
  int tb, c0, c1, part;
  bool issplit = (ji >= 8);
  if (!issplit) {
    tb = 7 - ji; part = 0;
    c0 = 0; c1 = 2 * tb + 2;
  } else {
    int e = (ji - 8) & 7;
    part = (ji - 8) >> 3;        // 0,1,2
    tb = 8 + e;
    int n = 2 * tb + 2;
    int s0 = (n + 2) / 3, s1 = (n + 1) / 3;
    c0 = (part == 0) ? 0 : ((part == 1) ? s0 : s0 + s1);
    c1 = (part == 0) ? s0 : ((part == 1) ? s0 + s1 : n);
  }
  int b = bh >> 4, h = bh & 15;
  int t = threadIdx.x, w = t >> 6, l = t & 63;
  int lg = l >> 4, lo = l & 15;
  const bf16* qp = q + (size_t)bh * SEQ * HEADDIM;
  const bf16* kp = k + (size_t)bh * SEQ * HEADDIM;
  const bf16* vp = vt + (size_t)bh * HEADDIM * SEQ;
  int q0 = tb * 128 + w * 16;
  int cd = q0 >> 6;        // this wave's diagonal chunk
  int diag_rhs = (w & 3) * 16 + lo;

  bf16x8 qf0 = *(const bf16x8*)&qp[(size_t)(q0 + lo) * HEADDIM + 8 * lg];
  bf16x8 qf1 = *(const bf16x8*)&qp[(size_t)(q0 + lo) * HEADDIM + 32 + 8 * lg];

  auto stage = [&](int bufi, int kv0) {
    int row = t >> 3, c16 = t & 7;
    int sc = c16 ^ (row & 7);
    async_load16(kp + (size_t)(kv0 + row) * HEADDIM + sc * 8, &Ks[bufi][t * 8]);
    async_load16(vp + (size_t)row * SEQ + kv0 + sc * 8, &Vs[bufi][t * 8]);
  };

  f32x4 o[4];
#pragma unroll
  for (int nt = 0; nt < 4; ++nt) o[nt] = (f32x4){0.f, 0.f, 0.f, 0.f};
  float lsum = 0.f;

  int buf = 0;
  stage(0, c0 * 64);
  __syncthreads();

  for (int c = c0; c < c1; ++c) {
    if (c + 1 < c1) stage(buf ^ 1, (c + 1) * 64);  // async prefetch

    if (c <= cd) {  // uniform per-wave: skip fully-masked chunks
      f32x4 s[4];
      __builtin_amdgcn_s_setprio(1);
#pragma unroll
      for (int nt = 0; nt < 4; ++nt) {
        s[nt] = (f32x4){0.f, 0.f, 0.f, 0.f};
        int krow = nt * 16 + lo;
        bf16x8 kf0 = *(const bf16x8*)&Ks[buf][krow * 64 + ((lg ^ (lo & 7)) * 8)];
        bf16x8 kf1 = *(const bf16x8*)&Ks[buf][krow * 64 + (((4 + lg) ^ (lo & 7)) * 8)];
        s[nt] = __builtin_amdgcn_mfma_f32_16x16x32_bf16(kf0, qf0, s[nt], 0, 0, 0);
        s[nt] = __builtin_amdgcn_mfma_f32_16x16x32_bf16(kf1, qf1, s[nt], 0, 0, 0);
      }
      __builtin_amdgcn_s_setprio(0);

      // hoist V fragment reads (LDS): latency hides under exp/pack below
      bf16x8 vf0[4], vf1[4];
#pragma unroll
      for (int nt = 0; nt < 4; ++nt) {
        int vrow = nt * 16 + lo;
        vf0[nt] = *(const bf16x8*)&Vs[buf][vrow * 64 + ((lg ^ (lo & 7)) * 8)];
        vf1[nt] = *(const bf16x8*)&Vs[buf][vrow * 64 + (((4 + lg) ^ (lo & 7)) * 8)];
      }

      if (c == cd) {  // causal mask, diagonal chunk only
#pragma unroll
        for (int nt = 0; nt < 4; ++nt)
#pragma unroll
          for (int r = 0; r < 4; ++r)
            s[nt][r] = (16 * nt + 4 * lg + r <= diag_rhs) ? s[nt][r] : -1e30f;
      }

      // fixed-M softmax + pack to bf16-pair words
      u32 W[4][2];
      float psum = 0.f;
#pragma unroll
      for (int nt = 0; nt < 4; ++nt) {
        float e0 = fexp2(fmaf(s[nt][0], C2, -MC));
        float e1 = fexp2(fmaf(s[nt][1], C2, -MC));
        float e2 = fexp2(fmaf(s[nt][2], C2, -MC));
        float e3 = fexp2(fmaf(s[nt][3], C2, -MC));
        psum += (e0 + e1) + (e2 + e3);
        bf16x2 w0, w1;
        w0[0] = (bf16)e0; w0[1] = (bf16)e1;
        w1[0] = (bf16)e2; w1[1] = (bf16)e3;
        W[nt][0] = __builtin_bit_cast(u32, w0);
        W[nt][1] = __builtin_bit_cast(u32, w1);
      }
      psum += __shfl_xor(psum, 16);
      psum += __shfl_xor(psum, 32);
      lsum += psum;

      // in-register P re-layout: C-frag -> A-frag via 2 swaps per word pair
      u32 t0 = W[0][0], t2 = W[1][0];
      pswap32(t0, t2); pswap16(t0, t2);
      u32 t1 = W[0][1], t3 = W[1][1];
      pswap32(t1, t3); pswap16(t1, t3);
      u32 u0 = W[2][0], u2 = W[3][0];
      pswap32(u0, u2); pswap16(u0, u2);
      u32 u1 = W[2][1], u3 = W[3][1];
      pswap32(u1, u3); pswap16(u1, u3);
      u32x4 pw0 = {t0, t1, t2, t3};
      u32x4 pw1 = {u0, u1, u2, u3};
      bf16x8 pf0 = __builtin_bit_cast(bf16x8, pw0);
      bf16x8 pf1 = __builtin_bit_cast(bf16x8, pw1);

      __builtin_amdgcn_s_setprio(1);
#pragma unroll
      for (int nt = 0; nt < 4; ++nt) {
        o[nt] = __builtin_amdgcn_mfma_f32_16x16x32_bf16(pf0, vf0[nt], o[nt], 0, 0, 0);
        o[nt] = __builtin_amdgcn_mfma_f32_16x16x32_bf16(pf1, vf1[nt], o[nt], 0, 0, 0);
      }
      __builtin_amdgcn_s_setprio(0);
    }

    __syncthreads();  // drains prefetch + all waves done with buf
    buf ^= 1;
  }

  if (!issplit) {
#pragma unroll
    for (int r = 0; r < 4; ++r) {
      float ls = __shfl(lsum, (l & 48) | (4 * lg + r));
      float inv = 1.0f / ls;
      int qrow = q0 + 4 * lg + r;
#pragma unroll
      for (int nt = 0; nt < 4; ++nt)
        attn[((size_t)b * SEQ + qrow) * D_MODEL + h * HEADDIM + nt * 16 + lo] =
            (bf16)(o[nt][r] * inv);
    }
  } else {  // write bf16 partial O + f32 partial lsum (part 0..2)
#pragma unroll
    for (int r = 0; r < 4; ++r) {
      float ls = __shfl(lsum, (l & 48) | (4 * lg + r));
      int prow = q0 - 1024 + 4 * lg + r;  // tb >= 8 -> q0 >= 1024
      if (lo == 0) plsum[(part << 15) + (bh << 10) + prow] = ls;
      size_t base = (((size_t)part * 32 + bh) * 1024 + prow) * 64;
#pragma unroll
      for (int nt = 0; nt < 4; ++nt)
        pO[base + nt * 16 + lo] = (bf16)o[nt][r];
    }
  }
}

// ------------- merge 3-way split-KV partials: rows s in [1024,2048) -------------
__global__ __launch_bounds__(256)
void merge_kernel(const bf16* __restrict__ pO, const float* __restrict__ plsum,
                  bf16* __restrict__ attn) {
  int tid = blockIdx.x * 256 + threadIdx.x;   // 262144 octets
  int bh = tid >> 13;
  int rem = tid & 8191;
  int srow = rem >> 3, q8 = rem & 7;
  int b = bh >> 4, h = bh & 15;
  int lidx = (bh << 10) + srow;
  float lsum = plsum[lidx] + plsum[(1 << 15) + lidx] + plsum[(2 << 15) + lidx];
  float inv = 1.0f / lsum;
  const size_t PSTRIDE = (size_t)32 * 1024 * 64;
  size_t base = (((size_t)bh) * 1024 + srow) * 64 + q8 * 8;
  bf16x8 a0 = *(const bf16x8*)&pO[base];
  bf16x8 a1 = *(const bf16x8*)&pO[PSTRIDE + base];
  bf16x8 a2 = *(const bf16x8*)&pO[2 * PSTRIDE + base];
  bf16x8 o;
#pragma unroll
  for (int e = 0; e < 8; ++e)
    o[e] = (bf16)((((float)a0[e] + (float)a1[e]) + (float)a2[e]) * inv);
  *(bf16x8*)&attn[((size_t)b * SEQ + 1024 + srow) * D_MODEL + h * HEADDIM + q8 * 8] = o;
}

extern "C" void kernel_launch(void* const* d_in, const int* in_sizes, int n_in,
                              void* d_out, int out_size, void* d_ws, size_t ws_size,
                              hipStream_t stream) {
  const float* x = (const float*)d_in[0];
  const float* ln_w = (const float*)d_in[1];
  const float* ln_b = (const float*)d_in[2];
  const float* wq = (const float*)d_in[3];
  const float* wk = (const float*)d_in[4];
  const float* wv = (const float*)d_in[5];
  const float* wo = (const float*)d_in[6];
  float* out = (float*)d_out;
  char* ws = (char*)d_ws;

  bf16* y     = (bf16*)(ws);                     // 8 MB (dead after QKV GEMM)
  bf16* WqkvT = (bf16*)(ws + (8u << 20));        // 6 MB (dead after QKV GEMM)
  bf16* woT   = (bf16*)(ws + (14u << 20));       // 2 MB (live until out-proj)
  bf16* qb    = (bf16*)(ws + (16u << 20));       // 8 MB  [b][h][s][e]
  bf16* kb    = (bf16*)(ws + (24u << 20));       // 8 MB  [b][h][s][e]
  bf16* vtb   = (bf16*)(ws + (32u << 20));       // 8 MB  [b][h][e][s]
  bf16* attnb = (bf16*)(ws + (40u << 20));       // 8 MB  [b*s][h*e]
  // 3-way split-KV scratch aliases y+WqkvT (dead before attn launches):
  bf16*  pO    = (bf16*)(ws);                    // 12 MB [3][32][1024][64] bf16
  float* plsum = (float*)(ws + (12u << 20));     // 384 KB [3][32][1024] f32

  // LayerNorm + all weight transposes, one launch
  ln_and_transpose<<<5120, 256, 0, stream>>>(x, ln_w, ln_b, y, wq, wk, wv, wo,
                                             WqkvT, woT);

  // fused QKV projection: [4096,1024] x [3072,1024]^T, 128x192 tiles (512 = 2/CU)
  gemm_bt<0, 128, 192><<<512, 256, 0, stream>>>(y, WqkvT, 16, qb, kb, vtb);

  // causal flash attention: 1024 blocks x 512 thr (4/CU), 3-way split-KV
  attn_kernel<<<dim3(1024), 512, 0, stream>>>(qb, kb, vtb, attnb, pO, plsum);

  // merge 3-way partials for rows s in [1024, 2048)
  merge_kernel<<<1024, 256, 0, stream>>>(pO, plsum, attnb);

  // output projection + residual: [4096,1024] x [1024,1024]^T + x, 64x128 tiles
  gemm_bt<2, 64, 128><<<512, 256, 0, stream>>>(attnb, woT, 8, out, (void*)x, nullptr);
}

// Round 20
// 98.646 us; speedup vs baseline: 2.0259x; 1.0292x over previous
//
#include <hip/hip_runtime.h>
#include <stdint.h>

typedef __bf16 bf16;
typedef __bf16 bf16x2 __attribute__((ext_vector_type(2)));
typedef __bf16 bf16x4 __attribute__((ext_vector_type(4)));
typedef __bf16 bf16x8 __attribute__((ext_vector_type(8)));
typedef float f32x4 __attribute__((ext_vector_type(4)));
typedef unsigned int u32;
typedef u32 u32x4 __attribute__((ext_vector_type(4)));

#define D_MODEL 1024
#define NHEADS 16
#define HEADDIM 64
#define SEQ 2048
#define NBATCH 2

__device__ __forceinline__ void async_load16(const void* g, void* l) {
  __builtin_amdgcn_global_load_lds(
      (__attribute__((address_space(1))) void*)g,
      (__attribute__((address_space(3))) void*)l, 16, 0, 0);
}

__device__ __forceinline__ float fexp2(float x) {
#if __has_builtin(__builtin_amdgcn_exp2f)
  return __builtin_amdgcn_exp2f(x);
#else
  return exp2f(x);
#endif
}

// x.hi32lanes <-> y.lo32lanes
__device__ __forceinline__ void pswap32(u32& x, u32& y) {
  asm("v_permlane32_swap_b32 %0, %1" : "+v"(x), "+v"(y));
}
// x.odd16groups <-> y.even16groups
__device__ __forceinline__ void pswap16(u32& x, u32& y) {
  asm("v_permlane16_swap_b32 %0, %1" : "+v"(x), "+v"(y));
}

// ------- merged LayerNorm + all-weight transpose (1 launch, 5120 blocks) -------
__global__ __launch_bounds__(256)
void ln_and_transpose(const float* __restrict__ x, const float* __restrict__ lw,
                      const float* __restrict__ lb, bf16* __restrict__ y,
                      const float* __restrict__ wq, const float* __restrict__ wk,
                      const float* __restrict__ wv, const float* __restrict__ wo,
                      bf16* __restrict__ WqkvT, bf16* __restrict__ woT) {
  __shared__ float tile[64][65];
  __shared__ float ps[4], pq[4];
  int t = threadIdx.x;
  if (blockIdx.x < 4096) {
    int row = blockIdx.x;
    const float4 v = ((const float4*)(x + (size_t)row * D_MODEL))[t];
    float s = v.x + v.y + v.z + v.w;
    float sq = v.x * v.x + v.y * v.y + v.z * v.z + v.w * v.w;
#pragma unroll
    for (int d = 1; d < 64; d <<= 1) {
      s += __shfl_xor(s, d);
      sq += __shfl_xor(sq, d);
    }
    if ((t & 63) == 0) { ps[t >> 6] = s; pq[t >> 6] = sq; }
    __syncthreads();
    s = ps[0] + ps[1] + ps[2] + ps[3];
    sq = pq[0] + pq[1] + pq[2] + pq[3];
    float mean = s * (1.0f / D_MODEL);
    float var = sq * (1.0f / D_MODEL) - mean * mean;
    float rstd = rsqrtf(var + 1e-5f);
    float4 wv4 = ((const float4*)lw)[t];
    float4 bv = ((const float4*)lb)[t];
    bf16x4 o;
    o[0] = (bf16)((v.x - mean) * rstd * wv4.x + bv.x);
    o[1] = (bf16)((v.y - mean) * rstd * wv4.y + bv.y);
    o[2] = (bf16)((v.z - mean) * rstd * wv4.z + bv.z);
    o[3] = (bf16)((v.w - mean) * rstd * wv4.w + bv.w);
    ((bf16x4*)(y + (size_t)row * D_MODEL))[t] = o;
    return;
  }
  int blk = blockIdx.x - 4096;
  const float* s;
  bf16* d;
  int src_ld, dst_ld;
  if (blk < 768) {
    int wsel = blk >> 8;
    int rem = blk & 255;
    int h = rem >> 4, tr = rem & 15;
    const float* w3 = (wsel == 0) ? wq : (wsel == 1) ? wk : wv;
    s = w3 + (size_t)h * 65536 + (size_t)tr * 64 * 64;
    d = WqkvT + ((size_t)wsel << 20) + (size_t)h * 65536 + (size_t)tr * 64;
    src_ld = 64; dst_ld = 1024;
  } else {
    int r = blk - 768;
    int tr = r >> 4, tc = r & 15;
    s = wo + (size_t)(tr * 64) * 1024 + tc * 64;
    d = woT + (size_t)(tc * 64) * 1024 + tr * 64;
    src_ld = 1024; dst_ld = 1024;
  }
  int rr = t >> 4;
  int cc = (t & 15) << 2;
#pragma unroll
  for (int i = 0; i < 4; ++i) {
    float4 v = *(const float4*)&s[(size_t)(rr + i * 16) * src_ld + cc];
    tile[rr + i * 16][cc + 0] = v.x;
    tile[rr + i * 16][cc + 1] = v.y;
    tile[rr + i * 16][cc + 2] = v.z;
    tile[rr + i * 16][cc + 3] = v.w;
  }
  __syncthreads();
#pragma unroll
  for (int i = 0; i < 4; ++i) {
    int drow = rr + i * 16;
    bf16x4 o;
    o[0] = (bf16)tile[cc + 0][drow];
    o[1] = (bf16)tile[cc + 1][drow];
    o[2] = (bf16)tile[cc + 2][drow];
    o[3] = (bf16)tile[cc + 3][drow];
    *(bf16x4*)&d[(size_t)drow * dst_ld + cc] = o;
  }
}

// ------------- GEMM: C[M][N] = A[M][K=1024] * Bt[N][K=1024]^T -------------
// MODE 0 (QKV): XCD-local 8x8 panel grouping (A 2MB + B 3MB per XCD ~ L2-fit).
// MODE 2 (out): linear cpx swizzle (unchanged).
template <int MODE, int BM, int BN>
__global__ __launch_bounds__(256)
void gemm_bt(const bf16* __restrict__ A, const bf16* __restrict__ Bt,
             int ntn, void* __restrict__ p0, void* __restrict__ p1,
             void* __restrict__ p2) {
  constexpr int NWR = BM / 64;
  constexpr int NWC = 4 / NWR;
  constexpr int NJ = BN / (16 * NWC);
  __shared__ __align__(16) bf16 As[2][BM * 64];
  __shared__ __align__(16) bf16 Bs[2][BN * 64];
  int bm, bn;
  if constexpr (MODE == 0) {
    // grid 512: XCD x = i&7 gets 8 bm x 8 bn panel (bijective)
    int xq = blockIdx.x & 7, j = blockIdx.x >> 3;
    bm = (xq >> 1) * 8 + (j >> 3);
    bn = (xq & 1) * 8 + (j & 7);
  } else {
    int cpx = gridDim.x >> 3;
    int wg = (blockIdx.x & 7) * cpx + (blockIdx.x >> 3);
    bm = wg / ntn;
    bn = wg % ntn;
  }
  int t = threadIdx.x;
  int w = t >> 6, l = t & 63;
  int lg = l >> 4, lo = l & 15;
  int wr = w / NWC, wc = w % NWC;
  const bf16* Ab = A + (size_t)bm * BM * 1024;
  const bf16* Bb = Bt + (size_t)bn * BN * 1024;
  f32x4 acc[4][NJ];
#pragma unroll
  for (int i = 0; i < 4; ++i)
#pragma unroll
    for (int j = 0; j < NJ; ++j) acc[i][j] = (f32x4){0.f, 0.f, 0.f, 0.f};

  auto stage = [&](int bufi, int k0) {
#pragma unroll
    for (int it = 0; it < BM / 32; ++it) {
      int flat = it * 2048 + t * 8;
      int row = flat >> 6, sc = ((flat & 63) >> 3) ^ (row & 7);
      async_load16(Ab + (size_t)row * 1024 + k0 + sc * 8, &As[bufi][it * 2048 + w * 512]);
    }
#pragma unroll
    for (int it = 0; it < BN / 32; ++it) {
      int flat = it * 2048 + t * 8;
      int row = flat >> 6, sc = ((flat & 63) >> 3) ^ (row & 7);
      async_load16(Bb + (size_t)row * 1024 + k0 + sc * 8, &Bs[bufi][it * 2048 + w * 512]);
    }
  };

  stage(0, 0);
  __syncthreads();
  int buf = 0;
  for (int k0 = 0; k0 < 1024; k0 += 64) {
    if (k0 + 64 < 1024) stage(buf ^ 1, k0 + 64);  // async prefetch over compute
#pragma unroll
    for (int kk = 0; kk < 2; ++kk) {
      bf16x8 af[4], bfr[NJ];
#pragma unroll
      for (int i = 0; i < 4; ++i) {
        int row = wr * 64 + i * 16 + lo;
        af[i] = *(const bf16x8*)&As[buf][row * 64 + (((4 * kk + lg) ^ (lo & 7)) * 8)];
      }
#pragma unroll
      for (int j = 0; j < NJ; ++j) {
        int row = wc * (NJ * 16) + j * 16 + lo;
        bfr[j] = *(const bf16x8*)&Bs[buf][row * 64 + (((4 * kk + lg) ^ (lo & 7)) * 8)];
      }
#pragma unroll
      for (int i = 0; i < 4; ++i)
#pragma unroll
        for (int j = 0; j < NJ; ++j)
          acc[i][j] = __builtin_amdgcn_mfma_f32_16x16x32_bf16(af[i], bfr[j], acc[i][j], 0, 0, 0);
    }
    __syncthreads();
    buf ^= 1;
  }

  int mbase = bm * BM + wr * 64;
  int nbase = bn * BN + wc * (NJ * 16);
#pragma unroll
  for (int i = 0; i < 4; ++i) {
#pragma unroll
    for (int j = 0; j < NJ; ++j) {
      int row0 = mbase + i * 16 + lg * 4;
      int col = nbase + j * 16 + lo;
      if (MODE == 0) {
        if (col < 2048) {  // q or k, [b][h][s][e]
          bf16* dst = (bf16*)(col < 1024 ? p0 : p1);
          int c = col & 1023;
          int h = c >> 6, e = c & 63;
#pragma unroll
          for (int r = 0; r < 4; ++r) {
            int row = row0 + r;
            dst[((((size_t)(row >> 11) * NHEADS + h) * SEQ) + (row & 2047)) * HEADDIM + e] =
                (bf16)acc[i][j][r];
          }
        } else {  // v^T [b][h][e][s], packed 4 consecutive s
          int c = col - 2048;
          int h = c >> 6, e = c & 63;
          int b_ = row0 >> 11, s_ = row0 & 2047;
          bf16x4 pk;
          pk[0] = (bf16)acc[i][j][0]; pk[1] = (bf16)acc[i][j][1];
          pk[2] = (bf16)acc[i][j][2]; pk[3] = (bf16)acc[i][j][3];
          *(bf16x4*)&((bf16*)p2)[(((size_t)b_ * NHEADS + h) * HEADDIM + e) * SEQ + s_] = pk;
        }
      } else {
#pragma unroll
        for (int r = 0; r < 4; ++r) {
          int row = row0 + r;
          float xr = ((const float*)p1)[(size_t)row * 1024 + col];
          ((float*)p0)[(size_t)row * 1024 + col] = acc[i][j][r] + xr;
        }
      }
    }
  }
}

// --- causal flash attention (R15 proven best: 2-way split-KV, 3 blocks/CU) ---
// 8 waves x 16 q-rows, 512 thr, grid 768, fixed-M softmax, split-KV on heavy
// tiles (tb 8..15), bh-per-XCD pinning, balanced CU triples {d, d+8, d+16}:
// (2d+2)+(16-d)+(16-d) = 34 units/CU for all d. In-register P via permlane
// swaps (no P LDS, 0 bank conflicts); K/V LDS-staged (32 KB, dbuf).
__global__ __launch_bounds__(512)
void attn_kernel(const bf16* __restrict__ q, const bf16* __restrict__ k,
                 const bf16* __restrict__ vt, bf16* __restrict__ attn,
                 bf16* __restrict__ pO, float* __restrict__ plsum) {
  __shared__ __align__(16) bf16 Ks[2][64 * 64];
  __shared__ __align__(16) bf16 Vs[2][64 * 64];
  const float C2 = 0.125f * 1.44269504f;
  const float MC = 128.0f * C2;  // fixed softmax shift
  int i = blockIdx.x;            // 0..767
  int slot = i >> 3;             // 0..95
  int bh = (i & 7) + 8 * (slot & 3);  // 0..31; i&7 == bh&7 -> one XCD per bh
  int ji = slot >> 2;            // 0..23 job index
  int split, tb;
  if (ji < 8) { split = 0; tb = ji; }
  else { split = 1 + ((ji >> 4) & 1); tb = 15 - (ji & 7); }
  int c0 = (split == 2) ? tb + 1 : 0;
  int c1 = (split == 1) ? tb + 1 : 2 * tb + 2;
  int b = bh >> 4, h = bh & 15;
  int t = threadIdx.x, w = t >> 6, l = t & 63;
  int lg = l >> 4, lo = l & 15;
  const bf16* qp = q + (size_t)bh * SEQ * HEADDIM;
  const bf16* kp = k + (size_t)bh * SEQ * HEADDIM;
  const bf16* vp = vt + (size_t)bh * HEADDIM * SEQ;
  int q0 = tb * 128 + w * 16;
  int cd = q0 >> 6;        // this wave's diagonal chunk
  int diag_rhs = (w & 3) * 16 + lo;

  bf16x8 qf0 = *(const bf16x8*)&qp[(size_t)(q0 + lo) * HEADDIM + 8 * lg];
  bf16x8 qf1 = *(const bf16x8*)&qp[(size_t)(q0 + lo) * HEADDIM + 32 + 8 * lg];

  auto stage = [&](int bufi, int kv0) {
    int row = t >> 3, c16 = t & 7;
    int sc = c16 ^ (row & 7);
    async_load16(kp + (size_t)(kv0 + row) * HEADDIM + sc * 8, &Ks[bufi][t * 8]);
    async_load16(vp + (size_t)row * SEQ + kv0 + sc * 8, &Vs[bufi][t * 8]);
  };

  f32x4 o[4];
#pragma unroll
  for (int nt = 0; nt < 4; ++nt) o[nt] = (f32x4){0.f, 0.f, 0.f, 0.f};
  float lsum = 0.f;

  int buf = 0;
  stage(0, c0 * 64);
  __syncthreads();

  for (int c = c0; c < c1; ++c) {
    if (c + 1 < c1) stage(buf ^ 1, (c + 1) * 64);  // async prefetch

    if (c <= cd) {  // uniform per-wave: skip fully-masked chunks
      f32x4 s[4];
      __builtin_amdgcn_s_setprio(1);
#pragma unroll
      for (int nt = 0; nt < 4; ++nt) {
        s[nt] = (f32x4){0.f, 0.f, 0.f, 0.f};
        int krow = nt * 16 + lo;
        bf16x8 kf0 = *(const bf16x8*)&Ks[buf][krow * 64 + ((lg ^ (lo & 7)) * 8)];
        bf16x8 kf1 = *(const bf16x8*)&Ks[buf][krow * 64 + (((4 + lg) ^ (lo & 7)) * 8)];
        s[nt] = __builtin_amdgcn_mfma_f32_16x16x32_bf16(kf0, qf0, s[nt], 0, 0, 0);
        s[nt] = __builtin_amdgcn_mfma_f32_16x16x32_bf16(kf1, qf1, s[nt], 0, 0, 0);
      }
      __builtin_amdgcn_s_setprio(0);

      // hoist V fragment reads (LDS): latency hides under exp/pack below
      bf16x8 vf0[4], vf1[4];
#pragma unroll
      for (int nt = 0; nt < 4; ++nt) {
        int vrow = nt * 16 + lo;
        vf0[nt] = *(const bf16x8*)&Vs[buf][vrow * 64 + ((lg ^ (lo & 7)) * 8)];
        vf1[nt] = *(const bf16x8*)&Vs[buf][vrow * 64 + (((4 + lg) ^ (lo & 7)) * 8)];
      }

      if (c == cd) {  // causal mask, diagonal chunk only
#pragma unroll
        for (int nt = 0; nt < 4; ++nt)
#pragma unroll
          for (int r = 0; r < 4; ++r)
            s[nt][r] = (16 * nt + 4 * lg + r <= diag_rhs) ? s[nt][r] : -1e30f;
      }

      // fixed-M softmax + pack to bf16-pair words
      u32 W[4][2];
      float psum = 0.f;
#pragma unroll
      for (int nt = 0; nt < 4; ++nt) {
        float e0 = fexp2(fmaf(s[nt][0], C2, -MC));
        float e1 = fexp2(fmaf(s[nt][1], C2, -MC));
        float e2 = fexp2(fmaf(s[nt][2], C2, -MC));
        float e3 = fexp2(fmaf(s[nt][3], C2, -MC));
        psum += (e0 + e1) + (e2 + e3);
        bf16x2 w0, w1;
        w0[0] = (bf16)e0; w0[1] = (bf16)e1;
        w1[0] = (bf16)e2; w1[1] = (bf16)e3;
        W[nt][0] = __builtin_bit_cast(u32, w0);
        W[nt][1] = __builtin_bit_cast(u32, w1);
      }
      psum += __shfl_xor(psum, 16);
      psum += __shfl_xor(psum, 32);
      lsum += psum;

      // in-register P re-layout: C-frag -> A-frag via 2 swaps per word pair
      u32 t0 = W[0][0], t2 = W[1][0];
      pswap32(t0, t2); pswap16(t0, t2);
      u32 t1 = W[0][1], t3 = W[1][1];
      pswap32(t1, t3); pswap16(t1, t3);
      u32 u0 = W[2][0], u2 = W[3][0];
      pswap32(u0, u2); pswap16(u0, u2);
      u32 u1 = W[2][1], u3 = W[3][1];
      pswap32(u1, u3); pswap16(u1, u3);
      u32x4 pw0 = {t0, t1, t2, t3};
      u32x4 pw1 = {u0, u1, u2, u3};
      bf16x8 pf0 = __builtin_bit_cast(bf16x8, pw0);
      bf16x8 pf1 = __builtin_bit_cast(bf16x8, pw1);

      __builtin_amdgcn_s_setprio(1);
#pragma unroll
      for (int nt = 0; nt < 4; ++nt) {
        o[nt] = __builtin_amdgcn_mfma_f32_16x16x32_bf16(pf0, vf0[nt], o[nt], 0, 0, 0);
        o[nt] = __builtin_amdgcn_mfma_f32_16x16x32_bf16(pf1, vf1[nt], o[nt], 0, 0, 0);
      }
      __builtin_amdgcn_s_setprio(0);
    }

    __syncthreads();  // drains prefetch + all waves done with buf
    buf ^= 1;
  }

  if (split == 0) {
#pragma unroll
    for (int r = 0; r < 4; ++r) {
      float ls = __shfl(lsum, (l & 48) | (4 * lg + r));
      float inv = 1.0f / ls;
      int qrow = q0 + 4 * lg + r;
#pragma unroll
      for (int nt = 0; nt < 4; ++nt)
        attn[((size_t)b * SEQ + qrow) * D_MODEL + h * HEADDIM + nt * 16 + lo] =
            (bf16)(o[nt][r] * inv);
    }
  } else {  // write bf16 partial O + f32 partial lsum
    int half = split - 1;
#pragma unroll
    for (int r = 0; r < 4; ++r) {
      float ls = __shfl(lsum, (l & 48) | (4 * lg + r));
      int prow = q0 - 1024 + 4 * lg + r;  // tb >= 8 -> q0 >= 1024
      if (lo == 0) plsum[(half << 15) + (bh << 10) + prow] = ls;
      size_t base = (((size_t)half * 32 + bh) * 1024 + prow) * 64;
#pragma unroll
      for (int nt = 0; nt < 4; ++nt)
        pO[base + nt * 16 + lo] = (bf16)o[nt][r];
    }
  }
}

// ------------- merge split-KV partials: rows s in [1024,2048) -------------
__global__ __launch_bounds__(256)
void merge_kernel(const bf16* __restrict__ pO, const float* __restrict__ plsum,
                  bf16* __restrict__ attn) {
  int tid = blockIdx.x * 256 + threadIdx.x;   // 262144 octets
  int bh = tid >> 13;
  int rem = tid & 8191;
  int srow = rem >> 3, q8 = rem & 7;
  int b = bh >> 4, h = bh & 15;
  float l = plsum[(bh << 10) + srow] + plsum[(1 << 15) + (bh << 10) + srow];
  float inv = 1.0f / l;
  size_t base = (((size_t)bh) * 1024 + srow) * 64 + q8 * 8;
  bf16x8 a1 = *(const bf16x8*)&pO[base];
  bf16x8 a2 = *(const bf16x8*)&pO[(size_t)32 * 1024 * 64 + base];
  bf16x8 o;
#pragma unroll
  for (int e = 0; e < 8; ++e)
    o[e] = (bf16)(((float)a1[e] + (float)a2[e]) * inv);
  *(bf16x8*)&attn[((size_t)b * SEQ + 1024 + srow) * D_MODEL + h * HEADDIM + q8 * 8] = o;
}

extern "C" void kernel_launch(void* const* d_in, const int* in_sizes, int n_in,
                              void* d_out, int out_size, void* d_ws, size_t ws_size,
                              hipStream_t stream) {
  const float* x = (const float*)d_in[0];
  const float* ln_w = (const float*)d_in[1];
  const float* ln_b = (const float*)d_in[2];
  const float* wq = (const float*)d_in[3];
  const float* wk = (const float*)d_in[4];
  const float* wv = (const float*)d_in[5];
  const float* wo = (const float*)d_in[6];
  float* out = (float*)d_out;
  char* ws = (char*)d_ws;

  bf16* y     = (bf16*)(ws);                     // 8 MB (dead after QKV GEMM)
  bf16* WqkvT = (bf16*)(ws + (8u << 20));        // 6 MB (dead after QKV GEMM)
  bf16* woT   = (bf16*)(ws + (14u << 20));       // 2 MB (live until out-proj)
  bf16* qb    = (bf16*)(ws + (16u << 20));       // 8 MB  [b][h][s][e]
  bf16* kb    = (bf16*)(ws + (24u << 20));       // 8 MB  [b][h][s][e]
  bf16* vtb   = (bf16*)(ws + (32u << 20));       // 8 MB  [b][h][e][s]
  bf16* attnb = (bf16*)(ws + (40u << 20));       // 8 MB  [b*s][h*e]
  // split-KV scratch aliases y/WqkvT (both dead before attn launches):
  bf16*  pO    = (bf16*)(ws);                    // 8 MB  [2][32][1024][64] bf16
  float* plsum = (float*)(ws + (8u << 20));      // 256 KB [2][32][1024] f32

  // LayerNorm + all weight transposes, one launch
  ln_and_transpose<<<5120, 256, 0, stream>>>(x, ln_w, ln_b, y, wq, wk, wv, wo,
                                             WqkvT, woT);

  // fused QKV projection: [4096,1024] x [3072,1024]^T, 128x192 tiles,
  // XCD-local 8x8 panel grouping (512 = 2/CU)
  gemm_bt<0, 128, 192><<<512, 256, 0, stream>>>(y, WqkvT, 16, qb, kb, vtb);

  // causal flash attention: 768 blocks x 512 thr (3/CU), 2-way split-KV
  attn_kernel<<<dim3(768), 512, 0, stream>>>(qb, kb, vtb, attnb, pO, plsum);

  // merge partials for rows s in [1024, 2048)
  merge_kernel<<<1024, 256, 0, stream>>>(pO, plsum, attnb);

  // output projection + residual: [4096,1024] x [1024,1024]^T + x, 64x128 tiles
  gemm_bt<2, 64, 128><<<512, 256, 0, stream>>>(attnb, woT, 8, out, (void*)x, nullptr);
}